// Round 9
// baseline (33.917 us; speedup 1.0000x reference)
//
#include <hip/hip_runtime.h>
#include <math.h>

#define CH_EPS 1e-6f
#define CH_N   4096
#define CH_BS  8
#define CH_JG  8                   // j-groups (part slots)
#define CH_CPB 2                   // chunks per block
#define CH_JCH 256                 // points per chunk
// block = 256 threads, TI=2 -> 512 i per block, 8 i-tiles
// grid = 8 it * 8 jg * 8 b * 2 dir = 1024 blocks -> 4 waves/SIMD

// part[dir][b][jg][i] : 2*8*8*4096 floats = 2 MB in d_ws
#define PART_IDX(dir, b, jg, i) \
    ((((size_t)(dir) * CH_BS + (b)) * CH_JG + (jg)) * CH_N + (i))

// evaluate 4 q-points (Q0..Q3) against both own points, update mins
#define CH_EVAL4(Q0, Q1, Q2, Q3)                                                        \
    {                                                                                   \
        const float e00 = fmaf(nx0, Q0.x, fmaf(ny0, Q0.y, fmaf(nz0, Q0.z, Q0.w)));      \
        const float e01 = fmaf(nx0, Q1.x, fmaf(ny0, Q1.y, fmaf(nz0, Q1.z, Q1.w)));      \
        const float e02 = fmaf(nx0, Q2.x, fmaf(ny0, Q2.y, fmaf(nz0, Q2.z, Q2.w)));      \
        const float e03 = fmaf(nx0, Q3.x, fmaf(ny0, Q3.y, fmaf(nz0, Q3.z, Q3.w)));      \
        const float e10 = fmaf(nx1, Q0.x, fmaf(ny1, Q0.y, fmaf(nz1, Q0.z, Q0.w)));      \
        const float e11 = fmaf(nx1, Q1.x, fmaf(ny1, Q1.y, fmaf(nz1, Q1.z, Q1.w)));      \
        const float e12 = fmaf(nx1, Q2.x, fmaf(ny1, Q2.y, fmaf(nz1, Q2.z, Q2.w)));      \
        const float e13 = fmaf(nx1, Q3.x, fmaf(ny1, Q3.y, fmaf(nz1, Q3.z, Q3.w)));      \
        ma0 = fminf(fminf(ma0, e00), e01);   /* v_min3_f32 */                           \
        mb0 = fminf(fminf(mb0, e02), e03);                                              \
        ma1 = fminf(fminf(ma1, e10), e11);                                              \
        mb1 = fminf(fminf(mb1, e12), e13);                                              \
    }

// ---------------- scan: per (i-tile, j-group) partial min ----------------
// dir 0: own=y, other=x ; dir 1: own=x, other=y
// d2 = p2 + (q2 - 2 p.q); track min_j (q2 - 2 p.q), add p2 at the end.
__global__ __launch_bounds__(256) void chamfer_scan_kernel(
    const float* __restrict__ x, const float* __restrict__ y,
    float* __restrict__ part, float* __restrict__ out) {
    const int tid = threadIdx.x;
    const int it  = blockIdx.x >> 3;    // i-tile [0,8)
    const int jg  = blockIdx.x & 7;     // j-group [0,8)
    const int b   = blockIdx.y;
    const int dir = blockIdx.z;

    // zero the output once per call (finalize dispatch runs after us)
    if (blockIdx.x == 0 && b == 0 && dir == 0 && tid < CH_BS) out[tid] = 0.0f;

    const float* own   = dir ? x : y;
    const float* other = dir ? y : x;

    // ---- own points: i0 and i0+256 (loaded once, reused for both chunks) ----
    const int i0 = it * 512 + tid;
    const int i1 = i0 + 256;
    const float* op0 = own + ((size_t)b * CH_N + i0) * 3;
    const float* op1 = own + ((size_t)b * CH_N + i1) * 3;
    const float px0 = op0[0], py0 = op0[1], pz0 = op0[2];
    const float px1 = op1[0], py1 = op1[1], pz1 = op1[2];
    const float p20 = px0 * px0 + py0 * py0 + pz0 * pz0;
    const float p21 = px1 * px1 + py1 * py1 + pz1 * pz1;
    const float nx0 = -2.0f * px0, ny0 = -2.0f * py0, nz0 = -2.0f * pz0;
    const float nx1 = -2.0f * px1, ny1 = -2.0f * py1, nz1 = -2.0f * pz1;

    float ma0 = 3.4e38f, mb0 = 3.4e38f, ma1 = 3.4e38f, mb1 = 3.4e38f;

    __shared__ float4 q4s[CH_JCH];   // 4 KB

#pragma unroll
    for (int c = 0; c < CH_CPB; ++c) {
        const int jc = jg * CH_CPB + c;
        if (c) __syncthreads();      // all waves done reading before restage
        {
            const float* qsrc = other + ((size_t)b * CH_N + (size_t)jc * CH_JCH + tid) * 3;
            const float qa = qsrc[0], qb = qsrc[1], qc = qsrc[2];
            q4s[tid] = make_float4(qa, qb, qc, qa * qa + qb * qb + qc * qc);
        }
        __syncthreads();

        // ---- software-pipelined inner scan: load next 4 before computing current 4 ----
        float4 A0 = q4s[0], A1 = q4s[1], A2 = q4s[2], A3 = q4s[3];
        float4 B0, B1, B2, B3;
        for (int j0 = 0; j0 < CH_JCH - 8; j0 += 8) {
            B0 = q4s[j0 + 4]; B1 = q4s[j0 + 5]; B2 = q4s[j0 + 6]; B3 = q4s[j0 + 7];
            CH_EVAL4(A0, A1, A2, A3);
            A0 = q4s[j0 + 8]; A1 = q4s[j0 + 9]; A2 = q4s[j0 + 10]; A3 = q4s[j0 + 11];
            CH_EVAL4(B0, B1, B2, B3);
        }
        // epilogue: A holds [248..251]; last 4 are [252..255]
        B0 = q4s[CH_JCH - 4]; B1 = q4s[CH_JCH - 3]; B2 = q4s[CH_JCH - 2]; B3 = q4s[CH_JCH - 1];
        CH_EVAL4(A0, A1, A2, A3);
        CH_EVAL4(B0, B1, B2, B3);
    }

    part[PART_IDX(dir, b, jg, i0)] = fminf(ma0, mb0) + p20;
    part[PART_IDX(dir, b, jg, i1)] = fminf(ma1, mb1) + p21;
}

// ---------------- finalize: min over j-groups, sqrt, mean, accumulate ----------------
// grid (CH_BS, 16 slices, 2 dirs) = 256 blocks; out zeroed by the scan dispatch.
__global__ __launch_bounds__(256) void chamfer_finalize_kernel(
    const float* __restrict__ part, float* __restrict__ out) {
    const int b   = blockIdx.x;
    const int sl  = blockIdx.y;
    const int dir = blockIdx.z;
    const int tid = threadIdx.x;
    const int i   = sl * 256 + tid;

    const size_t base = PART_IDX(dir, b, 0, i);
    float m = part[base];
#pragma unroll
    for (int jg = 1; jg < CH_JG; ++jg)
        m = fminf(m, part[base + (size_t)jg * CH_N]);
    float s = sqrtf(CH_EPS + fmaxf(m, 0.0f)) * (1.0f / (float)CH_N);

#pragma unroll
    for (int off = 32; off > 0; off >>= 1) s += __shfl_down(s, off, 64);

    __shared__ float wsum[4];
    if ((tid & 63) == 0) wsum[tid >> 6] = s;
    __syncthreads();
    if (tid == 0) atomicAdd(out + b, wsum[0] + wsum[1] + wsum[2] + wsum[3]);
}

extern "C" void kernel_launch(void* const* d_in, const int* in_sizes, int n_in,
                              void* d_out, int out_size, void* d_ws, size_t ws_size,
                              hipStream_t stream) {
    const float* x = (const float*)d_in[0];
    const float* y = (const float*)d_in[1];
    float* out  = (float*)d_out;
    float* part = (float*)d_ws;

    // scan: 8 i-tiles x 8 j-groups, 8 batches, 2 dirs = 1024 blocks
    chamfer_scan_kernel<<<dim3(8 * CH_JG, CH_BS, 2), dim3(256), 0, stream>>>(x, y, part, out);

    // finalize: 256 blocks
    chamfer_finalize_kernel<<<dim3(CH_BS, 16, 2), dim3(256), 0, stream>>>(part, out);
}

// Round 10
// 31.057 us; speedup vs baseline: 1.0921x; 1.0921x over previous
//
#include <hip/hip_runtime.h>
#include <math.h>

#define CH_EPS 1e-6f
#define CH_N   4096
#define CH_BS  8
#define CH_JC  16                  // j-chunks
#define CH_JCH (CH_N / CH_JC)      // 256 points per chunk
#define CH_TI  4                   // own points per thread
// block = 256 threads, TI=4 -> 1024 i per block, 4 i-tiles
// blocks = 4 * 16 * 8 * 2 = 1024

// part[dir][b][jc][i] : 2*8*16*4096 floats = 4 MB in d_ws
#define PART_IDX(dir, b, jc, i) \
    ((((size_t)(dir) * CH_BS + (b)) * CH_JC + (jc)) * CH_N + (i))

typedef float v2f __attribute__((ext_vector_type(2)));

static __device__ __forceinline__ v2f pk_fma(v2f a, v2f b, v2f c) {
#if __has_builtin(__builtin_elementwise_fma)
    return __builtin_elementwise_fma(a, b, c);
#else
    v2f r; r.x = fmaf(a.x, b.x, c.x); r.y = fmaf(a.y, b.y, c.y); return r;
#endif
}

// ---------------- scan: per (i-tile, j-chunk) partial min ----------------
// dir 0: own=y, other=x ; dir 1: own=x, other=y
// d2 = p2 + (q2 - 2 p.q); track min_j (q2 - 2 p.q) via packed-fp32 fma,
// add p2 at the end.
__global__ __launch_bounds__(256) void chamfer_scan_kernel(
    const float* __restrict__ x, const float* __restrict__ y,
    float* __restrict__ part, float* __restrict__ out) {
    const int tid = threadIdx.x;
    const int it  = blockIdx.x >> 4;    // i-tile [0,4)
    const int jc  = blockIdx.x & 15;    // j-chunk [0,16)
    const int b   = blockIdx.y;
    const int dir = blockIdx.z;

    // zero the output once per call (finalize dispatch runs after us)
    if (blockIdx.x == 0 && b == 0 && dir == 0 && tid < CH_BS) out[tid] = 0.0f;

    const float* own   = dir ? x : y;
    const float* other = dir ? y : x;

    // ---- stage j-chunk into LDS, SoA: qx | qy | qz | q2 ----
    __shared__ alignas(16) float qxs[CH_JCH];
    __shared__ alignas(16) float qys[CH_JCH];
    __shared__ alignas(16) float qzs[CH_JCH];
    __shared__ alignas(16) float qws[CH_JCH];
    {
        const float* qsrc = other + ((size_t)b * CH_N + (size_t)jc * CH_JCH + tid) * 3;
        const float qa = qsrc[0], qb = qsrc[1], qc = qsrc[2];
        qxs[tid] = qa; qys[tid] = qb; qzs[tid] = qc;
        qws[tid] = qa * qa + qb * qb + qc * qc;
    }
    __syncthreads();

    // ---- own points: i0 + t*256, t in [0,4) ----
    const int i0 = it * 1024 + tid;
    v2f nx2[CH_TI], ny2[CH_TI], nz2[CH_TI];
    float p2[CH_TI], mn[CH_TI];
#pragma unroll
    for (int t = 0; t < CH_TI; ++t) {
        const float* op = own + ((size_t)b * CH_N + i0 + t * 256) * 3;
        const float px = op[0], py = op[1], pz = op[2];
        p2[t] = px * px + py * py + pz * pz;
        const float nx = -2.0f * px, ny = -2.0f * py, nz = -2.0f * pz;
        nx2[t] = (v2f){nx, nx}; ny2[t] = (v2f){ny, ny}; nz2[t] = (v2f){nz, nz};
        mn[t] = 3.4e38f;
    }

    // ---- inner scan: 4 broadcast ds_read_b128 (SoA) -> 2 packed pair-groups ----
    for (int j0 = 0; j0 < CH_JCH; j0 += 4) {
        const float4 X = *(const float4*)&qxs[j0];
        const float4 Y = *(const float4*)&qys[j0];
        const float4 Z = *(const float4*)&qzs[j0];
        const float4 W = *(const float4*)&qws[j0];
        const v2f xlo = (v2f){X.x, X.y}, xhi = (v2f){X.z, X.w};
        const v2f ylo = (v2f){Y.x, Y.y}, yhi = (v2f){Y.z, Y.w};
        const v2f zlo = (v2f){Z.x, Z.y}, zhi = (v2f){Z.z, Z.w};
        const v2f wlo = (v2f){W.x, W.y}, whi = (v2f){W.z, W.w};
#pragma unroll
        for (int t = 0; t < CH_TI; ++t) {
            const v2f elo = pk_fma(nx2[t], xlo, pk_fma(ny2[t], ylo, pk_fma(nz2[t], zlo, wlo)));
            const v2f ehi = pk_fma(nx2[t], xhi, pk_fma(ny2[t], yhi, pk_fma(nz2[t], zhi, whi)));
            // fminf(fminf(a,b),c) -> v_min3_f32
            mn[t] = fminf(fminf(mn[t], elo.x), elo.y);
            mn[t] = fminf(fminf(mn[t], ehi.x), ehi.y);
        }
    }

#pragma unroll
    for (int t = 0; t < CH_TI; ++t) {
        part[PART_IDX(dir, b, jc, i0 + t * 256)] = mn[t] + p2[t];
    }
}

// ---------------- finalize: min over chunks, sqrt, mean, accumulate ----------------
// grid (CH_BS, 16 slices, 2 dirs) = 256 blocks; out zeroed by the scan dispatch.
__global__ __launch_bounds__(256) void chamfer_finalize_kernel(
    const float* __restrict__ part, float* __restrict__ out) {
    const int b   = blockIdx.x;
    const int sl  = blockIdx.y;
    const int dir = blockIdx.z;
    const int tid = threadIdx.x;
    const int i   = sl * 256 + tid;

    const size_t base = PART_IDX(dir, b, 0, i);
    float m = part[base];
#pragma unroll
    for (int jc = 1; jc < CH_JC; ++jc)
        m = fminf(m, part[base + (size_t)jc * CH_N]);
    float s = sqrtf(CH_EPS + fmaxf(m, 0.0f)) * (1.0f / (float)CH_N);

#pragma unroll
    for (int off = 32; off > 0; off >>= 1) s += __shfl_down(s, off, 64);

    __shared__ float wsum[4];
    if ((tid & 63) == 0) wsum[tid >> 6] = s;
    __syncthreads();
    if (tid == 0) atomicAdd(out + b, wsum[0] + wsum[1] + wsum[2] + wsum[3]);
}

extern "C" void kernel_launch(void* const* d_in, const int* in_sizes, int n_in,
                              void* d_out, int out_size, void* d_ws, size_t ws_size,
                              hipStream_t stream) {
    const float* x = (const float*)d_in[0];
    const float* y = (const float*)d_in[1];
    float* out  = (float*)d_out;
    float* part = (float*)d_ws;

    // scan: 4 i-tiles x 16 j-chunks, 8 batches, 2 dirs = 1024 blocks
    chamfer_scan_kernel<<<dim3(4 * CH_JC, CH_BS, 2), dim3(256), 0, stream>>>(x, y, part, out);

    // finalize: 256 blocks
    chamfer_finalize_kernel<<<dim3(CH_BS, 16, 2), dim3(256), 0, stream>>>(part, out);
}